// Round 2
// baseline (114.701 us; speedup 1.0000x reference)
//
#include <hip/hip_runtime.h>
#include <hip/hip_bf16.h>

#define N_ENT 100000
#define NB 16
#define DIM 128
#define TILE 64
#define RSTRIDE 132      // 128+4 floats: per-lane b128 reads conflict-free
#define N_TILES ((N_ENT + TILE - 1) / TILE)   // 1563

// Workspace lives in module statics (d_ws poison fills are unconditional —
// confirmed by round-1 A/B — but statics are free and every slot is written
// before read on every launch).
__device__ float g_head[NB * DIM];            // 8 KB
__device__ float g_partials[NB * N_TILES];    // 100 KB

// ---------------- kernel 1: head = normalize(ent[e1]) + normalize(rel[r]) ----
__global__ __launch_bounds__(128) void head_kernel(
    const int* __restrict__ e1, const int* __restrict__ rel,
    const float* __restrict__ ent, const float* __restrict__ relemb)
{
    int b = blockIdx.x, d = threadIdx.x;
    float ev = ent[e1[b] * DIM + d];
    float rv = relemb[rel[b] * DIM + d];
    __shared__ float s1[DIM], s2[DIM];
    s1[d] = ev * ev;
    s2[d] = rv * rv;
    __syncthreads();
    for (int s = 64; s > 0; s >>= 1) {
        if (d < s) { s1[d] += s1[d + s]; s2[d] += s2[d + s]; }
        __syncthreads();
    }
    float ne = fmaxf(sqrtf(s1[0]), 1e-12f);
    float nr = fmaxf(sqrtf(s2[0]), 1e-12f);
    g_head[b * DIM + d] = ev / ne + rv / nr;
}

// ---------------- kernel 2: fused dist + exp; 4 waves/block, 4 b per wave ---
// Round-2 restructure: each ds_read_b128 of an entity row now feeds FOUR
// batch rows instead of two, halving total LDS traffic (the co-critical
// per-CU resource: was 7.8 us vs 8.1 us HBM). 256 thr = 4 waves; wave w
// computes b in [4w,4w+4). LDS 34 KB -> 4 blocks/CU = 16 waves/CU; the lost
// TLP vs the 512-thr version is replaced by ILP: launch_bounds(256,4) allows
// 128 VGPR so the compiler can pipeline j-iterations, and each ds_read feeds
// 32 independent VALU ops (4 accumulator chains).
__global__ __launch_bounds__(256, 4) void dist_kernel(
    const float* __restrict__ ent, float* __restrict__ out)
{
    __shared__ float ldsRow[TILE * RSTRIDE];   // 33792 B
    __shared__ float ldsInv[TILE];             // 256 B

    const int tid  = threadIdx.x;
    const int lane = tid & 63;
    const int wv   = __builtin_amdgcn_readfirstlane(tid >> 6);  // uniform 0..3
    const int bbase = wv * 4;
    const int n0 = blockIdx.x * TILE;
    const float4* __restrict__ hg = (const float4*)g_head;  // uniform-indexed

    // stage rows: 2048 float4 over 256 threads -> 8 each, coalesced
    {
        const float4* eg = (const float4*)ent;
        #pragma unroll
        for (int i = 0; i < 8; i++) {
            int g = tid + i * 256;             // float4 index within tile
            int r = g >> 5, c = g & 31;
            int gr = n0 + r;
            if (gr >= N_ENT) gr = N_ENT - 1;   // clamp for partial last tile
            float4 v = eg[gr * (DIM / 4) + c];
            *(float4*)&ldsRow[r * RSTRIDE + c * 4] = v;
        }
    }
    __syncthreads();

    // cooperative row norms: 4 threads per row, 32 floats each
    {
        int r = tid >> 2, q = tid & 3;
        const float* p = &ldsRow[r * RSTRIDE + q * 32];
        float s = 0.f;
        #pragma unroll
        for (int k = 0; k < 8; k++) {
            float4 v = *(const float4*)&p[k * 4];
            s = fmaf(v.x, v.x, s); s = fmaf(v.y, v.y, s);
            s = fmaf(v.z, v.z, s); s = fmaf(v.w, v.w, s);
        }
        s += __shfl_down(s, 2);
        s += __shfl_down(s, 1);
        if (q == 0) ldsInv[r] = 1.0f / fmaxf(sqrtf(s), 1e-12f);
    }
    __syncthreads();

    const float inv = ldsInv[lane];
    const float* rp = &ldsRow[lane * RSTRIDE];

    float a0 = 0.f, a1 = 0.f, a2 = 0.f, a3 = 0.f;
    #pragma unroll
    for (int j = 0; j < DIM / 4; j++) {
        float4 v  = *(const float4*)&rp[j * 4];
        float4 q0 = hg[(bbase + 0) * (DIM / 4) + j];   // uniform -> s_load
        float4 q1 = hg[(bbase + 1) * (DIM / 4) + j];
        float4 q2 = hg[(bbase + 2) * (DIM / 4) + j];
        float4 q3 = hg[(bbase + 3) * (DIM / 4) + j];
        a0 += fabsf(fmaf(-v.x, inv, q0.x)) + fabsf(fmaf(-v.y, inv, q0.y))
            + fabsf(fmaf(-v.z, inv, q0.z)) + fabsf(fmaf(-v.w, inv, q0.w));
        a1 += fabsf(fmaf(-v.x, inv, q1.x)) + fabsf(fmaf(-v.y, inv, q1.y))
            + fabsf(fmaf(-v.z, inv, q1.z)) + fabsf(fmaf(-v.w, inv, q1.w));
        a2 += fabsf(fmaf(-v.x, inv, q2.x)) + fabsf(fmaf(-v.y, inv, q2.y))
            + fabsf(fmaf(-v.z, inv, q2.z)) + fabsf(fmaf(-v.w, inv, q2.w));
        a3 += fabsf(fmaf(-v.x, inv, q3.x)) + fabsf(fmaf(-v.y, inv, q3.y))
            + fabsf(fmaf(-v.z, inv, q3.z)) + fabsf(fmaf(-v.w, inv, q3.w));
    }

    // exp; no max-subtract needed: dist <= 34, sums < 6e19 << fp32 max
    const int n = n0 + lane;
    const bool valid = (n < N_ENT);
    float e0 = valid ? __expf(a0) : 0.f;
    float e1 = valid ? __expf(a1) : 0.f;
    float e2 = valid ? __expf(a2) : 0.f;
    float e3 = valid ? __expf(a3) : 0.f;
    if (valid) {
        out[(bbase + 0) * N_ENT + n] = e0;     // lane-contiguous: coalesced
        out[(bbase + 1) * N_ENT + n] = e1;
        out[(bbase + 2) * N_ENT + n] = e2;
        out[(bbase + 3) * N_ENT + n] = e3;
    }

#define WRED(x) { x += __shfl_down(x, 32); x += __shfl_down(x, 16); \
                  x += __shfl_down(x, 8);  x += __shfl_down(x, 4);  \
                  x += __shfl_down(x, 2);  x += __shfl_down(x, 1); }
    WRED(e0) WRED(e1) WRED(e2) WRED(e3)
#undef WRED
    if (lane == 0) {   // b-major: partials[b*N_TILES + block] — no contention
        g_partials[(bbase + 0) * N_TILES + blockIdx.x] = e0;
        g_partials[(bbase + 1) * N_TILES + blockIdx.x] = e1;
        g_partials[(bbase + 2) * N_TILES + blockIdx.x] = e2;
        g_partials[(bbase + 3) * N_TILES + blockIdx.x] = e3;
    }
}

// ---------------- kernel 3: out *= 1/sum(partials[b][*]) --------------------
// Each block redundantly reduces its row's 1563 partials (6.3 KB, L2-hot).
__global__ __launch_bounds__(256) void scale_kernel(float* __restrict__ out)
{
    const int b = blockIdx.y;
    const int tid = threadIdx.x;

    // load my output chunk first (overlaps with the reduction)
    const int i = blockIdx.x * 256 + tid;              // float4 index
    float4 v = make_float4(0.f, 0.f, 0.f, 0.f);
    float4* row = (float4*)&out[b * N_ENT];
    const bool valid = (i < N_ENT / 4);
    if (valid) v = row[i];

    float s = 0.f;
    for (int k = tid; k < N_TILES; k += 256) s += g_partials[b * N_TILES + k];
    s += __shfl_down(s, 32); s += __shfl_down(s, 16);
    s += __shfl_down(s, 8);  s += __shfl_down(s, 4);
    s += __shfl_down(s, 2);  s += __shfl_down(s, 1);
    __shared__ float red[4];
    if ((tid & 63) == 0) red[tid >> 6] = s;
    __syncthreads();
    const float invS = 1.0f / (red[0] + red[1] + red[2] + red[3]);

    if (valid) {
        v.x *= invS; v.y *= invS; v.z *= invS; v.w *= invS;
        row[i] = v;
    }
}

extern "C" void kernel_launch(void* const* d_in, const int* in_sizes, int n_in,
                              void* d_out, int out_size, void* d_ws, size_t ws_size,
                              hipStream_t stream) {
    const int*   e1     = (const int*)d_in[0];
    const int*   rel    = (const int*)d_in[1];
    const float* ent    = (const float*)d_in[4];
    const float* relemb = (const float*)d_in[5];
    float* out = (float*)d_out;
    (void)d_ws; (void)ws_size;

    head_kernel<<<16, 128, 0, stream>>>(e1, rel, ent, relemb);
    dist_kernel<<<N_TILES, 256, 0, stream>>>(ent, out);
    scale_kernel<<<dim3((N_ENT / 4 + 255) / 256, NB), 256, 0, stream>>>(out);
}

// Round 3
// 108.995 us; speedup vs baseline: 1.0523x; 1.0523x over previous
//
#include <hip/hip_runtime.h>
#include <hip/hip_bf16.h>

#define N_ENT 100000
#define NB 16
#define DIM 128
#define TILE 64
#define RSTRIDE 132      // 128+4 floats: per-lane b128 reads conflict-free
#define N_TILES ((N_ENT + TILE - 1) / TILE)   // 1563

// Workspace lives in module statics (d_ws poison fills are unconditional —
// round-1 A/B — but statics are free and every slot is written before read
// on every launch).
__device__ float g_head[NB * DIM];            // 8 KB
__device__ float g_partials[NB * N_TILES];    // 100 KB

// ---------------- kernel 1: head = normalize(ent[e1]) + normalize(rel[r]) ----
__global__ __launch_bounds__(128) void head_kernel(
    const int* __restrict__ e1, const int* __restrict__ rel,
    const float* __restrict__ ent, const float* __restrict__ relemb)
{
    int b = blockIdx.x, d = threadIdx.x;
    float ev = ent[e1[b] * DIM + d];
    float rv = relemb[rel[b] * DIM + d];
    __shared__ float s1[DIM], s2[DIM];
    s1[d] = ev * ev;
    s2[d] = rv * rv;
    __syncthreads();
    for (int s = 64; s > 0; s >>= 1) {
        if (d < s) { s1[d] += s1[d + s]; s2[d] += s2[d + s]; }
        __syncthreads();
    }
    float ne = fmaxf(sqrtf(s1[0]), 1e-12f);
    float nr = fmaxf(sqrtf(s2[0]), 1e-12f);
    g_head[b * DIM + d] = ev / ne + rv / nr;
}

// ---------------- kernel 2: fused dist + exp; 8 waves/block, 2 b per wave ---
// Round-1 structure (measured best: 32 waves/CU): 1563 blocks, one 64-entity
// tile each. Block = 512 thr = 8 waves; wave w computes b in [2w,2w+2) for
// all 64 entities (lane = entity). LDS 34 KB -> 4 blocks/CU = 100% occupancy.
// Round-3 change: norm computation FUSED into staging (each thread loads 4
// float4 of the SAME row, sq-accumulates in-register, 8-lane shfl reduce).
// Deletes the 64-instr/block LDS norm re-read pass (~2 us aggregate of the
// binding LDS resource) and one __syncthreads. Main loop untouched.
__global__ __launch_bounds__(512, 8) void dist_kernel(
    const float* __restrict__ ent, float* __restrict__ out)
{
    __shared__ float ldsRow[TILE * RSTRIDE];   // 33792 B
    __shared__ float ldsInv[TILE];             // 256 B

    const int tid  = threadIdx.x;
    const int lane = tid & 63;
    const int wv   = __builtin_amdgcn_readfirstlane(tid >> 6);  // uniform 0..7
    const int bbase = wv * 2;
    const int n0 = blockIdx.x * TILE;
    const float4* __restrict__ hg = (const float4*)g_head;  // uniform-indexed

    // stage rows AND compute norms in one pass:
    // thread t owns row r = t>>3, eighth q = t&7; loads float4 cols
    // q, q+8, q+16, q+24. Per instr a wave touches 8 rows x 128B contiguous
    // = 16 cache lines for 1 KB -> fully coalesced. Sq-sum stays in regs.
    {
        const float4* eg = (const float4*)ent;
        const int r = tid >> 3, q = tid & 7;
        int gr = n0 + r;
        if (gr >= N_ENT) gr = N_ENT - 1;       // clamp for partial last tile
        const float4* grow = eg + gr * (DIM / 4);
        float s = 0.f;
        #pragma unroll
        for (int i = 0; i < 4; i++) {
            float4 v = grow[q + 8 * i];
            *(float4*)&ldsRow[r * RSTRIDE + (q + 8 * i) * 4] = v;
            s = fmaf(v.x, v.x, s); s = fmaf(v.y, v.y, s);
            s = fmaf(v.z, v.z, s); s = fmaf(v.w, v.w, s);
        }
        s += __shfl_down(s, 4);
        s += __shfl_down(s, 2);
        s += __shfl_down(s, 1);
        if (q == 0) ldsInv[r] = 1.0f / fmaxf(sqrtf(s), 1e-12f);
    }
    __syncthreads();

    const float inv = ldsInv[lane];
    const float* rp = &ldsRow[lane * RSTRIDE];

    float a0 = 0.f, a1 = 0.f;
    #pragma unroll
    for (int j = 0; j < DIM / 4; j++) {
        float4 v  = *(const float4*)&rp[j * 4];
        float4 q0 = hg[(bbase + 0) * (DIM / 4) + j];   // uniform -> s_load
        float4 q1 = hg[(bbase + 1) * (DIM / 4) + j];
        a0 += fabsf(fmaf(-v.x, inv, q0.x)) + fabsf(fmaf(-v.y, inv, q0.y))
            + fabsf(fmaf(-v.z, inv, q0.z)) + fabsf(fmaf(-v.w, inv, q0.w));
        a1 += fabsf(fmaf(-v.x, inv, q1.x)) + fabsf(fmaf(-v.y, inv, q1.y))
            + fabsf(fmaf(-v.z, inv, q1.z)) + fabsf(fmaf(-v.w, inv, q1.w));
    }

    // exp; no max-subtract needed: dist <= 34, sums < 6e19 << fp32 max
    const int n = n0 + lane;
    const bool valid = (n < N_ENT);
    float e0 = valid ? __expf(a0) : 0.f;
    float e1 = valid ? __expf(a1) : 0.f;
    if (valid) {
        out[(bbase + 0) * N_ENT + n] = e0;     // lane-contiguous: coalesced
        out[(bbase + 1) * N_ENT + n] = e1;
    }

#define WRED(x) { x += __shfl_down(x, 32); x += __shfl_down(x, 16); \
                  x += __shfl_down(x, 8);  x += __shfl_down(x, 4);  \
                  x += __shfl_down(x, 2);  x += __shfl_down(x, 1); }
    WRED(e0) WRED(e1)
#undef WRED
    if (lane == 0) {   // b-major: partials[b*N_TILES + block] — no contention
        g_partials[(bbase + 0) * N_TILES + blockIdx.x] = e0;
        g_partials[(bbase + 1) * N_TILES + blockIdx.x] = e1;
    }
}

// ---------------- kernel 3: out *= 1/sum(partials[b][*]) --------------------
// Each block redundantly reduces its row's 1563 partials (6.3 KB, L2-hot).
__global__ __launch_bounds__(256) void scale_kernel(float* __restrict__ out)
{
    const int b = blockIdx.y;
    const int tid = threadIdx.x;

    // load my output chunk first (overlaps with the reduction)
    const int i = blockIdx.x * 256 + tid;              // float4 index
    float4 v = make_float4(0.f, 0.f, 0.f, 0.f);
    float4* row = (float4*)&out[b * N_ENT];
    const bool valid = (i < N_ENT / 4);
    if (valid) v = row[i];

    float s = 0.f;
    for (int k = tid; k < N_TILES; k += 256) s += g_partials[b * N_TILES + k];
    s += __shfl_down(s, 32); s += __shfl_down(s, 16);
    s += __shfl_down(s, 8);  s += __shfl_down(s, 4);
    s += __shfl_down(s, 2);  s += __shfl_down(s, 1);
    __shared__ float red[4];
    if ((tid & 63) == 0) red[tid >> 6] = s;
    __syncthreads();
    const float invS = 1.0f / (red[0] + red[1] + red[2] + red[3]);

    if (valid) {
        v.x *= invS; v.y *= invS; v.z *= invS; v.w *= invS;
        row[i] = v;
    }
}

extern "C" void kernel_launch(void* const* d_in, const int* in_sizes, int n_in,
                              void* d_out, int out_size, void* d_ws, size_t ws_size,
                              hipStream_t stream) {
    const int*   e1     = (const int*)d_in[0];
    const int*   rel    = (const int*)d_in[1];
    const float* ent    = (const float*)d_in[4];
    const float* relemb = (const float*)d_in[5];
    float* out = (float*)d_out;
    (void)d_ws; (void)ws_size;

    head_kernel<<<16, 128, 0, stream>>>(e1, rel, ent, relemb);
    dist_kernel<<<N_TILES, 512, 0, stream>>>(ent, out);
    scale_kernel<<<dim3((N_ENT / 4 + 255) / 256, NB), 256, 0, stream>>>(out);
}